// Round 1
// baseline (237.254 us; speedup 1.0000x reference)
//
#include <hip/hip_runtime.h>

// 16-qubit statevector, iSWAP(t) on qubits (3,7), qubit 0 = MSB.
// bit positions: qubit 3 -> bit 12, qubit 7 -> bit 8.
constexpr int DIM    = 1 << 16;    // 65536
constexpr int BATCH  = 256;        // f32 per row; 64 float4
constexpr int COLS   = BATCH / 4;  // 64 float4 columns per row
constexpr int BIT_HI = 1 << 12;    // qubit 3
constexpr int BIT_LO = 1 << 8;     // qubit 7
constexpr int MASK_BOTH = BIT_HI | BIT_LO;  // 0x1100

constexpr int NPAIR     = DIM / 4;        // 16384 (0,1)-indices
constexpr int NCOPY     = DIM / 2;        // 32768 indices with b12==b8
constexpr int PAIR_WORK = NPAIR * COLS;   // 1,048,576 threads
constexpr int COPY_WORK = NCOPY * COLS;   // 2,097,152 threads
constexpr int TOTAL     = PAIR_WORK + COPY_WORK;

// Insert 14 low bits of b into positions {0..7, 9..11, 13..15}
// (leaves bits 8 and 12 zero).
__device__ __forceinline__ int expand14(int b) {
    return (b & 0x00FF) | ((b & 0x0700) << 1) | ((b & 0x3800) << 2);
}

__global__ __launch_bounds__(256) void iswap_kernel(
    const float* __restrict__ sr, const float* __restrict__ si,
    const float* __restrict__ tp, float* __restrict__ out)
{
    const int gid = blockIdx.x * blockDim.x + threadIdx.x;
    float* __restrict__ out_r = out;
    float* __restrict__ out_i = out + (size_t)DIM * BATCH;

    if (gid < PAIR_WORK) {
        float s, c;
        sincosf(tp[0], &s, &c);
        const int col = gid & (COLS - 1);
        const int p   = gid >> 6;                 // [0, NPAIR)
        const int i01 = expand14(p) | BIT_LO;     // b12=0, b8=1
        const int i10 = i01 ^ MASK_BOTH;          // b12=1, b8=0
        const size_t o01 = (size_t)i01 * BATCH + (size_t)col * 4;
        const size_t o10 = (size_t)i10 * BATCH + (size_t)col * 4;

        const float4 r01 = *(const float4*)(sr + o01);
        const float4 m01 = *(const float4*)(si + o01);
        const float4 r10 = *(const float4*)(sr + o10);
        const float4 m10 = *(const float4*)(si + o10);

        float4 nr01, ni01, nr10, ni10;
        // new01 = c*old01 - i*s*old10 ; new10 = c*old10 - i*s*old01
#define MIX(f)                                   \
        nr01.f = fmaf(c, r01.f,  s * m10.f);     \
        ni01.f = fmaf(c, m01.f, -s * r10.f);     \
        nr10.f = fmaf(c, r10.f,  s * m01.f);     \
        ni10.f = fmaf(c, m10.f, -s * r01.f);
        MIX(x) MIX(y) MIX(z) MIX(w)
#undef MIX

        *(float4*)(out_r + o01) = nr01;
        *(float4*)(out_i + o01) = ni01;
        *(float4*)(out_r + o10) = nr10;
        *(float4*)(out_i + o10) = ni10;
    } else {
        const int g   = gid - PAIR_WORK;          // [0, COPY_WORK)
        const int col = g & (COLS - 1);
        const int q   = g >> 6;                   // [0, NCOPY)
        const int d   = q >> 14;                  // 0 -> (0,0), 1 -> (1,1)
        const int idx = expand14(q & 0x3FFF) | (d ? MASK_BOTH : 0);
        const size_t o = (size_t)idx * BATCH + (size_t)col * 4;
        *(float4*)(out_r + o) = *(const float4*)(sr + o);
        *(float4*)(out_i + o) = *(const float4*)(si + o);
    }
}

extern "C" void kernel_launch(void* const* d_in, const int* in_sizes, int n_in,
                              void* d_out, int out_size, void* d_ws, size_t ws_size,
                              hipStream_t stream) {
    const float* sr = (const float*)d_in[0];
    const float* si = (const float*)d_in[1];
    const float* t  = (const float*)d_in[2];
    float* out = (float*)d_out;

    static_assert(TOTAL % 256 == 0, "grid sizing");
    iswap_kernel<<<dim3(TOTAL / 256), dim3(256), 0, stream>>>(sr, si, t, out);
}

// Round 3
// 223.430 us; speedup vs baseline: 1.0619x; 1.0619x over previous
//
#include <hip/hip_runtime.h>

// 16-qubit statevector, iSWAP(t) on qubits (3,7), qubit 0 = MSB.
// bit positions: qubit 3 -> bit 12, qubit 7 -> bit 8.
constexpr int DIM    = 1 << 16;    // 65536
constexpr int BATCH  = 256;        // f32 per row; 64 float4
constexpr int COLS   = BATCH / 4;  // 64 float4 columns per row
constexpr int BIT_HI = 1 << 12;    // qubit 3
constexpr int BIT_LO = 1 << 8;     // qubit 7
constexpr int MASK_BOTH = BIT_HI | BIT_LO;  // 0x1100

constexpr int NPAIR     = DIM / 4;        // 16384 (0,1)-indices
constexpr int NCOPY     = DIM / 2;        // 32768 indices with b12==b8
constexpr int PAIR_WORK = NPAIR * COLS;   // 1,048,576 threads
constexpr int COPY_WORK = NCOPY * COLS;   // 2,097,152 threads
constexpr int TOTAL     = PAIR_WORK + COPY_WORK;

// Clang native vector type: __builtin_nontemporal_* requires a native
// vector, not HIP's float4 class.
typedef float v4f __attribute__((ext_vector_type(4)));

// Insert 14 low bits of b into positions {0..7, 9..11, 13..15}
// (leaves bits 8 and 12 zero).
__device__ __forceinline__ int expand14(int b) {
    return (b & 0x00FF) | ((b & 0x0700) << 1) | ((b & 0x3800) << 2);
}

__global__ __launch_bounds__(256) void iswap_kernel(
    const float* __restrict__ sr, const float* __restrict__ si,
    const float* __restrict__ tp, float* __restrict__ out)
{
    const int gid = blockIdx.x * blockDim.x + threadIdx.x;
    float* __restrict__ out_r = out;
    float* __restrict__ out_i = out + (size_t)DIM * BATCH;

    if (gid < PAIR_WORK) {
        // Fast trig: t in [0, 2pi), threshold 0.108 -> __sinf/__cosf are
        // plenty accurate and avoid libm sincos's pointer-output path.
        const float tv = tp[0];
        const float s = __sinf(tv);
        const float c = __cosf(tv);

        const int col = gid & (COLS - 1);
        const int p   = gid >> 6;                 // [0, NPAIR)
        const int i01 = expand14(p) | BIT_LO;     // b12=0, b8=1
        const int i10 = i01 ^ MASK_BOTH;          // b12=1, b8=0
        const size_t o01 = (size_t)i01 * BATCH + (size_t)col * 4;
        const size_t o10 = (size_t)i10 * BATCH + (size_t)col * 4;

        // Streaming data, zero reuse: nontemporal to avoid L2 churn.
        const v4f r01 = __builtin_nontemporal_load((const v4f*)(sr + o01));
        const v4f m01 = __builtin_nontemporal_load((const v4f*)(si + o01));
        const v4f r10 = __builtin_nontemporal_load((const v4f*)(sr + o10));
        const v4f m10 = __builtin_nontemporal_load((const v4f*)(si + o10));

        // new01 = c*old01 - i*s*old10 ; new10 = c*old10 - i*s*old01
        // re(new01) = c*r01 + s*m10 ; im(new01) = c*m01 - s*r10  (sym. for 10)
        const v4f nr01 = c * r01 + s * m10;
        const v4f ni01 = c * m01 - s * r10;
        const v4f nr10 = c * r10 + s * m01;
        const v4f ni10 = c * m10 - s * r01;

        __builtin_nontemporal_store(nr01, (v4f*)(out_r + o01));
        __builtin_nontemporal_store(ni01, (v4f*)(out_i + o01));
        __builtin_nontemporal_store(nr10, (v4f*)(out_r + o10));
        __builtin_nontemporal_store(ni10, (v4f*)(out_i + o10));
    } else {
        const int g   = gid - PAIR_WORK;          // [0, COPY_WORK)
        const int col = g & (COLS - 1);
        const int q   = g >> 6;                   // [0, NCOPY)
        const int d   = q >> 14;                  // 0 -> (0,0), 1 -> (1,1)
        const int idx = expand14(q & 0x3FFF) | (d ? MASK_BOTH : 0);
        const size_t o = (size_t)idx * BATCH + (size_t)col * 4;
        const v4f vr = __builtin_nontemporal_load((const v4f*)(sr + o));
        const v4f vi = __builtin_nontemporal_load((const v4f*)(si + o));
        __builtin_nontemporal_store(vr, (v4f*)(out_r + o));
        __builtin_nontemporal_store(vi, (v4f*)(out_i + o));
    }
}

extern "C" void kernel_launch(void* const* d_in, const int* in_sizes, int n_in,
                              void* d_out, int out_size, void* d_ws, size_t ws_size,
                              hipStream_t stream) {
    const float* sr = (const float*)d_in[0];
    const float* si = (const float*)d_in[1];
    const float* t  = (const float*)d_in[2];
    float* out = (float*)d_out;

    static_assert(TOTAL % 256 == 0, "grid sizing");
    iswap_kernel<<<dim3(TOTAL / 256), dim3(256), 0, stream>>>(sr, si, t, out);
}